// Round 18
// baseline (79.413 us; speedup 1.0000x reference)
//
#include <hip/hip_runtime.h>
#include <hip/hip_bf16.h>
#include <math.h>

#define N_NODES 50000
#define N_EDGES 800000
#define IN_F 256
#define OUT_F 64

#define BKT 256            // nodes per bucket
#define NB 196             // ceil(50000/256)
#define CAP 6144           // fixed per-bucket capacity (mean 4096, sigma 64)
#define PARTA_BLOCKS 400   // 800000/400 = 2000 edges/block
#define EPB (N_EDGES / PARTA_BLOCKS)   // 2000
#define GEMM_BM 32         // 32 KB LDS -> 4 blocks/CU

typedef __attribute__((ext_vector_type(8))) short bf16x8;
typedef __attribute__((ext_vector_type(4))) float f32x4;

__device__ __forceinline__ ushort f2bf(float x) {
    __hip_bfloat16 b = __float2bfloat16(x);   // RNE
    return *reinterpret_cast<ushort*>(&b);
}
__device__ __forceinline__ float bf_lo(uint v) { return __uint_as_float(v << 16); }
__device__ __forceinline__ float bf_hi(uint v) { return __uint_as_float(v & 0xffff0000u); }

// ---------------------------------------------------------------------------
// 0) prep: block 0 zeros bcntD+bcntS; blocks 1..8 pack W into bf16 MFMA
//    B-frag layout.
// ---------------------------------------------------------------------------
__global__ __launch_bounds__(256) void prep_kernel(int* __restrict__ bcnt,
                                                   const float* __restrict__ W,
                                                   ushort* __restrict__ Wpk) {
    const int tid = threadIdx.x;
    if (blockIdx.x == 0) {
        for (int i = tid; i < 2 * NB; i += 256) bcnt[i] = 0;
    } else {
        const int gid = (blockIdx.x - 1) * 256 + tid;   // 0..2047
        const int lane = gid & 63;
        const int ct = (gid >> 6) & 3;
        const int step = gid >> 8;
        const int kg = lane >> 4;
        const int n = lane & 15;
        const float* base = W + (size_t)(step * 32 + kg * 8) * OUT_F + ct * 16 + n;
        union { ushort u[8]; uint4 v; } pk;
        #pragma unroll
        for (int j = 0; j < 8; ++j) pk.u[j] = f2bf(base[(size_t)j * OUT_F]);
        ((uint4*)Wpk)[gid] = pk.v;
    }
}

// ---------------------------------------------------------------------------
// 1) partA: dual bucket-partition with LDS-staged write combining.
//    No edge-slice LDS cache (place pass re-reads the L2-hot slice) ->
//    ~26 KB LDS -> 4 blocks/CU (was 3 at 41.8 KB).
// ---------------------------------------------------------------------------
__global__ __launch_bounds__(512) void partA_kernel(const int* __restrict__ src,
                                                    const int* __restrict__ dst,
                                                    int* __restrict__ bcntD,
                                                    int* __restrict__ bcntS,
                                                    uint* __restrict__ pairsD,
                                                    ushort* __restrict__ srcloc) {
    __shared__ uint stgD[EPB];            // 8 KB   staged pairs, bucket-sorted
    __shared__ ushort bktD[EPB];          // 4 KB   bucket id per staged slot
    __shared__ ushort stgS[EPB];          // 4 KB   staged src-locals
    __shared__ ushort bktS[EPB];          // 4 KB
    __shared__ int lcntD[256], lcntS[256];    // counts -> cursors
    __shared__ int ldofD[256], ldofS[256];    // local exclusive offsets
    __shared__ int lbaseD[NB], lbaseS[NB];    // global base offsets (in-bucket)
    __shared__ int wtotD[4], wtotS[4];
    const int tid = threadIdx.x;
    const int n4 = EPB / 4;   // 500

    for (int i = tid; i < 256; i += 512) { lcntD[i] = 0; lcntS[i] = 0; }
    __syncthreads();

    // count buckets (slice becomes L2-hot for the place pass)
    const int4* t4 = (const int4*)(dst + (size_t)blockIdx.x * EPB);
    const int4* s4 = (const int4*)(src + (size_t)blockIdx.x * EPB);
    for (int i = tid; i < n4; i += 512) {
        const int4 d = t4[i];
        const int4 s = s4[i];
        atomicAdd(&lcntD[d.x >> 8], 1); atomicAdd(&lcntS[s.x >> 8], 1);
        atomicAdd(&lcntD[d.y >> 8], 1); atomicAdd(&lcntS[s.y >> 8], 1);
        atomicAdd(&lcntD[d.z >> 8], 1); atomicAdd(&lcntS[s.z >> 8], 1);
        atomicAdd(&lcntD[d.w >> 8], 1); atomicAdd(&lcntS[s.w >> 8], 1);
    }
    __syncthreads();

    // reserve global bucket regions
    for (int i = tid; i < NB; i += 512) {
        const int cD = lcntD[i];
        lbaseD[i] = cD ? atomicAdd(&bcntD[i], cD) : 0;
        const int cS = lcntS[i];
        lbaseS[i] = cS ? atomicAdd(&bcntS[i], cS) : 0;
    }

    // block exclusive scan of both count arrays (waves 0-3)
    if (tid < 256) {
        const int lane = tid & 63;
        const int wave = tid >> 6;
        const int vD = lcntD[tid], vS = lcntS[tid];
        int iD = vD, iS = vS;
        #pragma unroll
        for (int d = 1; d < 64; d <<= 1) {
            const int uD = __shfl_up(iD, d, 64);
            const int uS = __shfl_up(iS, d, 64);
            if (lane >= d) { iD += uD; iS += uS; }
        }
        if (lane == 63) { wtotD[wave] = iD; wtotS[wave] = iS; }
        ldofD[tid] = iD - vD;
        ldofS[tid] = iS - vS;
    }
    __syncthreads();
    if (tid < 256) {
        const int wave = tid >> 6;
        int woD = 0, woS = 0;
        #pragma unroll
        for (int w = 0; w < 4; ++w)
            if (w < wave) { woD += wtotD[w]; woS += wtotS[w]; }
        ldofD[tid] += woD;
        ldofS[tid] += woS;
        lcntD[tid] = 0;      // reuse as cursors
        lcntS[tid] = 0;
    }
    __syncthreads();

    // place into LDS staging, sorted by bucket (re-read slice from L2)
    for (int i = tid; i < n4; i += 512) {
        const int4 d = t4[i];
        const int4 s = s4[i];
        int bx, pos, sl;
        #define PLACE(dd, ss)                                                  \
            bx = (dd) >> 8; pos = atomicAdd(&lcntD[bx], 1);                    \
            sl = ldofD[bx] + pos;                                              \
            stgD[sl] = ((uint)((dd) & 255) << 16) | (uint)(ss);                \
            bktD[sl] = (ushort)bx;                                             \
            bx = (ss) >> 8; pos = atomicAdd(&lcntS[bx], 1);                    \
            sl = ldofS[bx] + pos;                                              \
            stgS[sl] = (ushort)((ss) & 255);                                   \
            bktS[sl] = (ushort)bx;
        PLACE(d.x, s.x)
        PLACE(d.y, s.y)
        PLACE(d.z, s.z)
        PLACE(d.w, s.w)
        #undef PLACE
    }
    __syncthreads();

    // write out in staging order: consecutive lanes -> consecutive dests
    for (int i = tid; i < EPB; i += 512) {
        int b = bktD[i];
        pairsD[(size_t)b * CAP + lbaseD[b] + (i - ldofD[b])] = stgD[i];
        b = bktS[i];
        srcloc[(size_t)b * CAP + lbaseS[b] + (i - ldofS[b])] = stgS[i];
    }
}

// ---------------------------------------------------------------------------
// 2) bucket: fused degB + partB, 1024 threads (round-16, kept).
// ---------------------------------------------------------------------------
__global__ __launch_bounds__(1024) void bucket_kernel(const ushort* __restrict__ srcloc,
                                                      const int* __restrict__ bcntS,
                                                      float* __restrict__ normS,
                                                      const uint* __restrict__ pairsD,
                                                      const int* __restrict__ bcntD,
                                                      int* __restrict__ ptr,
                                                      int* __restrict__ indeg,
                                                      ushort* __restrict__ sorted_src) {
    __shared__ int cnt[BKT];
    __shared__ int loff[BKT];
    __shared__ int wtot[4];
    const int bb = blockIdx.x;
    const int tid = threadIdx.x;
    const int node = bb * BKT + tid;   // valid meaning only for tid<256

    // --- phase 1: out-degree -> normS ---
    if (tid < BKT) cnt[tid] = 0;
    __syncthreads();
    const int nS = bcntS[bb];
    const ushort* sp = srcloc + (size_t)bb * CAP;
    for (int i = tid; i < nS; i += 1024) atomicAdd(&cnt[sp[i]], 1);
    __syncthreads();
    if (tid < BKT && node < N_NODES)
        normS[node] = rsqrtf(fmaxf((float)cnt[tid], 1.0f));
    __syncthreads();

    // --- phase 2: dst sort ---
    if (tid < BKT) cnt[tid] = 0;
    __syncthreads();
    const int nD = bcntD[bb];
    const uint* pb = pairsD + (size_t)bb * CAP;
    for (int i = tid; i < nD; i += 1024) atomicAdd(&cnt[pb[i] >> 16], 1);
    __syncthreads();

    // scan on waves 0-3
    if (tid < BKT) {
        const int lane = tid & 63;
        const int wave = tid >> 6;
        const int v = cnt[tid];
        int incl = v;
        #pragma unroll
        for (int d = 1; d < 64; d <<= 1) {
            int u = __shfl_up(incl, d, 64);
            if (lane >= d) incl += u;
        }
        if (lane == 63) wtot[wave] = incl;
        loff[tid] = incl - v;            // temp: intra-wave exclusive
    }
    __syncthreads();
    if (tid < BKT) {
        const int wave = tid >> 6;
        int woff = 0;
        #pragma unroll
        for (int w = 0; w < 4; ++w)
            if (w < wave) woff += wtot[w];
        const int ex = woff + loff[tid];
        loff[tid] = ex;
        const int v = cnt[tid];
        cnt[tid] = 0;                    // reuse as per-local cursor
        if (node < N_NODES) { ptr[node] = bb * CAP + ex; indeg[node] = v; }
    }
    __syncthreads();

    for (int i = tid; i < nD; i += 1024) {
        const uint p = pb[i];
        const int local = (int)(p >> 16);
        const int pos = atomicAdd(&cnt[local], 1);
        sorted_src[(size_t)bb * CAP + loff[local] + pos] = (ushort)(p & 0xFFFFu);
    }
}

// ---------------------------------------------------------------------------
// 3) gemm: h_raw = bf16(feat @ W) via MFMA, LDS-staged A, BM=32 (round-16).
// ---------------------------------------------------------------------------
__global__ __launch_bounds__(256) void gemm_kernel(const float* __restrict__ feat,
                                                   const ushort* __restrict__ Wpk,
                                                   ushort* __restrict__ h) {
    __shared__ float ftile[GEMM_BM * IN_F];   // 32 KB
    const int tid = threadIdx.x;
    const int lane = tid & 63;
    const int wave = tid >> 6;
    const int m = lane & 15;
    const int g = lane >> 4;
    const int rowBase = blockIdx.x * GEMM_BM;
    const char* fb = (const char*)feat;

    #pragma unroll
    for (int it = 0; it < 8; ++it) {
        const int R = it * 4 + wave;                        // tile row 0..31
        const int off = (lane * 16) ^ ((R & 7) << 4);       // swizzled src chunk
        int grow = rowBase + R;
        if (grow >= N_NODES) grow = N_NODES - 1;            // clamp (dup row)
        __builtin_amdgcn_global_load_lds(
            (const __attribute__((address_space(1))) void*)(fb + ((size_t)grow << 10) + off),
            (__attribute__((address_space(3))) void*)((char*)ftile + it * 4096 + wave * 1024),
            16, 0, 0);
    }
    __syncthreads();

    const int rowHalf = wave & 1;              // 0/1: rows 0-15 / 16-31
    const int colHalf = wave >> 1;             // 0/1: cols 0-31 / 32-63

    f32x4 acc[2];
    acc[0] = (f32x4){0.f, 0.f, 0.f, 0.f};
    acc[1] = (f32x4){0.f, 0.f, 0.f, 0.f};

    const int Rr = rowHalf * 16 + m;           // A-frag row within tile
    const int swz = (Rr & 7) << 4;
    const char* rowb = (const char*)ftile + (Rr << 10);
    const bf16x8* wp = (const bf16x8*)Wpk;

    #pragma unroll
    for (int step = 0; step < 8; ++step) {
        const int kb = step * 128 + g * 32;
        const float4 a0 = *(const float4*)(rowb + (kb ^ swz));
        const float4 a1 = *(const float4*)(rowb + ((kb + 16) ^ swz));
        bf16x8 aa;
        aa[0] = (short)f2bf(a0.x); aa[1] = (short)f2bf(a0.y);
        aa[2] = (short)f2bf(a0.z); aa[3] = (short)f2bf(a0.w);
        aa[4] = (short)f2bf(a1.x); aa[5] = (short)f2bf(a1.y);
        aa[6] = (short)f2bf(a1.z); aa[7] = (short)f2bf(a1.w);
        #pragma unroll
        for (int ct = 0; ct < 2; ++ct)
            acc[ct] = __builtin_amdgcn_mfma_f32_16x16x32_bf16(
                aa, wp[(step * 4 + colHalf * 2 + ct) * 64 + lane], acc[ct], 0, 0, 0);
    }

    // C-frag: col = colHalf*32 + ct*16 + m, row = rowBase + rowHalf*16 + g*4 + j
    #pragma unroll
    for (int j = 0; j < 4; ++j) {
        const int row = rowBase + rowHalf * 16 + g * 4 + j;
        if (row < N_NODES) {
            #pragma unroll
            for (int ct = 0; ct < 2; ++ct)
                h[(size_t)row * OUT_F + colHalf * 32 + ct * 16 + m] = f2bf(acc[ct][j]);
        }
    }
}

// ---------------------------------------------------------------------------
// 4) Gather + epilogue: one wave per dst node, EIGHTH-wave per edge
//    (8 lanes x 16 B uint4 = full 128 B h-row), 8 edges in flight/iter.
//    Reduce across the 8 edge slots via shfl_xor 8/16/32.
// ---------------------------------------------------------------------------
__global__ __launch_bounds__(256) void gather_kernel(const int* __restrict__ ptr,
                                                     const int* __restrict__ indeg,
                                                     const ushort* __restrict__ sorted_src,
                                                     const float* __restrict__ normS,
                                                     const ushort* __restrict__ h,
                                                     const float* __restrict__ b,
                                                     float* __restrict__ out) {
    const int lane = threadIdx.x & 63;
    const int o = lane & 7;            // 16B chunk within row: cols o*8..o*8+7
    const int g = lane >> 3;           // edge slot 0..7
    int nid = (int)((blockIdx.x * (size_t)blockDim.x + threadIdx.x) >> 6);
    if (nid >= N_NODES) return;
    nid = __builtin_amdgcn_readfirstlane(nid);

    const int beg = ptr[nid];
    const int deg = indeg[nid];

    float a0 = 0.f, a1 = 0.f, a2 = 0.f, a3 = 0.f;
    float a4 = 0.f, a5 = 0.f, a6 = 0.f, a7 = 0.f;
    const int nfull = deg >> 3;
    int e = beg + g;
    #pragma unroll 2
    for (int i = 0; i < nfull; ++i) {
        const int s = (int)sorted_src[e];
        e += 8;
        const float ns = normS[s];
        const uint4 v = *(const uint4*)(h + (size_t)s * OUT_F + o * 8);
        a0 = fmaf(ns, bf_lo(v.x), a0); a1 = fmaf(ns, bf_hi(v.x), a1);
        a2 = fmaf(ns, bf_lo(v.y), a2); a3 = fmaf(ns, bf_hi(v.y), a3);
        a4 = fmaf(ns, bf_lo(v.z), a4); a5 = fmaf(ns, bf_hi(v.z), a5);
        a6 = fmaf(ns, bf_lo(v.w), a6); a7 = fmaf(ns, bf_hi(v.w), a7);
    }
    const int rem = deg & 7;
    if (g < rem) {
        const int s = (int)sorted_src[beg + (deg & ~7) + g];
        const float ns = normS[s];
        const uint4 v = *(const uint4*)(h + (size_t)s * OUT_F + o * 8);
        a0 = fmaf(ns, bf_lo(v.x), a0); a1 = fmaf(ns, bf_hi(v.x), a1);
        a2 = fmaf(ns, bf_lo(v.y), a2); a3 = fmaf(ns, bf_hi(v.y), a3);
        a4 = fmaf(ns, bf_lo(v.z), a4); a5 = fmaf(ns, bf_hi(v.z), a5);
        a6 = fmaf(ns, bf_lo(v.w), a6); a7 = fmaf(ns, bf_hi(v.w), a7);
    }
    // combine the 8 edge-slot groups (flip g bits: xor 8, 16, 32)
    #pragma unroll
    for (int d = 8; d <= 32; d <<= 1) {
        a0 += __shfl_xor(a0, d, 64); a1 += __shfl_xor(a1, d, 64);
        a2 += __shfl_xor(a2, d, 64); a3 += __shfl_xor(a3, d, 64);
        a4 += __shfl_xor(a4, d, 64); a5 += __shfl_xor(a5, d, 64);
        a6 += __shfl_xor(a6, d, 64); a7 += __shfl_xor(a7, d, 64);
    }

    if (g == 0) {
        const float norm = rsqrtf(fmaxf((float)deg, 1.0f));
        const float4 b0 = *(const float4*)(b + o * 8);
        const float4 b1 = *(const float4*)(b + o * 8 + 4);
        float4 o0, o1;
        o0.x = 1.0f / (1.0f + expf(-(a0 * norm + b0.x)));
        o0.y = 1.0f / (1.0f + expf(-(a1 * norm + b0.y)));
        o0.z = 1.0f / (1.0f + expf(-(a2 * norm + b0.z)));
        o0.w = 1.0f / (1.0f + expf(-(a3 * norm + b0.w)));
        o1.x = 1.0f / (1.0f + expf(-(a4 * norm + b1.x)));
        o1.y = 1.0f / (1.0f + expf(-(a5 * norm + b1.y)));
        o1.z = 1.0f / (1.0f + expf(-(a6 * norm + b1.z)));
        o1.w = 1.0f / (1.0f + expf(-(a7 * norm + b1.w)));
        float* op = out + (size_t)nid * OUT_F + o * 8;
        *(float4*)op = o0;
        *(float4*)(op + 4) = o1;
    }
}

// ---------------------------------------------------------------------------
extern "C" void kernel_launch(void* const* d_in, const int* in_sizes, int n_in,
                              void* d_out, int out_size, void* d_ws, size_t ws_size,
                              hipStream_t stream) {
    const float* feat = (const float*)d_in[0];
    const int* src    = (const int*)d_in[1];
    const int* dst    = (const int*)d_in[2];
    const float* W    = (const float*)d_in[3];
    const float* b    = (const float*)d_in[4];
    float* out = (float*)d_out;

    char* ws = (char*)d_ws;
    size_t off = 0;
    ushort* h = (ushort*)(ws + off);        off += (size_t)N_NODES * OUT_F * 2;  // 6.4 MB
    float* normS = (float*)(ws + off);      off += (size_t)N_NODES * 4;          // 200 KB
    int* indeg = (int*)(ws + off);          off += (size_t)N_NODES * 4;          // 200 KB
    int* ptr = (int*)(ws + off);            off += (size_t)N_NODES * 4;          // 200 KB
    int* bcnt = (int*)(ws + off);           off += (size_t)2 * NB * 4;           // bcntD|bcntS
    ushort* Wpk = (ushort*)(ws + off);      off += (size_t)IN_F * OUT_F * 2;     // 32 KB
    uint* pairsD = (uint*)(ws + off);       off += (size_t)NB * CAP * 4;         // 4.8 MB
    ushort* srcloc = (ushort*)(ws + off);   off += (size_t)NB * CAP * 2;         // 2.4 MB
    ushort* sorted_src = (ushort*)(ws + off); off += (size_t)NB * CAP * 2;       // 2.4 MB
    int* bcntD = bcnt;
    int* bcntS = bcnt + NB;

    prep_kernel<<<9, 256, 0, stream>>>(bcnt, W, Wpk);

    partA_kernel<<<PARTA_BLOCKS, 512, 0, stream>>>(src, dst, bcntD, bcntS, pairsD, srcloc);

    bucket_kernel<<<NB, 1024, 0, stream>>>(srcloc, bcntS, normS,
                                           pairsD, bcntD, ptr, indeg, sorted_src);

    gemm_kernel<<<(N_NODES + GEMM_BM - 1) / GEMM_BM, 256, 0, stream>>>(feat, Wpk, h);

    gather_kernel<<<(N_NODES * 64 + 255) / 256, 256, 0, stream>>>(
        ptr, indeg, sorted_src, normS, h, b, out);
}

// Round 19
// 74.794 us; speedup vs baseline: 1.0618x; 1.0618x over previous
//
#include <hip/hip_runtime.h>
#include <hip/hip_bf16.h>
#include <math.h>

#define N_NODES 50000
#define N_EDGES 800000
#define IN_F 256
#define OUT_F 64

#define BKT 256            // nodes per bucket
#define NB 196             // ceil(50000/256)
#define CAP 6144           // fixed per-bucket capacity (mean 4096, sigma 64)
#define PARTA_BLOCKS 400   // 800000/400 = 2000 edges/block
#define EPB (N_EDGES / PARTA_BLOCKS)   // 2000
#define GEMM_BM 32         // 32 KB LDS -> 4 blocks/CU

typedef __attribute__((ext_vector_type(8))) short bf16x8;
typedef __attribute__((ext_vector_type(4))) float f32x4;

__device__ __forceinline__ ushort f2bf(float x) {
    __hip_bfloat16 b = __float2bfloat16(x);   // RNE
    return *reinterpret_cast<ushort*>(&b);
}
__device__ __forceinline__ float bf_lo(uint v) { return __uint_as_float(v << 16); }
__device__ __forceinline__ float bf_hi(uint v) { return __uint_as_float(v & 0xffff0000u); }

// ---------------------------------------------------------------------------
// 0) prep: block 0 zeros bcntD+bcntS; blocks 1..8 pack W into bf16 MFMA
//    B-frag layout.
// ---------------------------------------------------------------------------
__global__ __launch_bounds__(256) void prep_kernel(int* __restrict__ bcnt,
                                                   const float* __restrict__ W,
                                                   ushort* __restrict__ Wpk) {
    const int tid = threadIdx.x;
    if (blockIdx.x == 0) {
        for (int i = tid; i < 2 * NB; i += 256) bcnt[i] = 0;
    } else {
        const int gid = (blockIdx.x - 1) * 256 + tid;   // 0..2047
        const int lane = gid & 63;
        const int ct = (gid >> 6) & 3;
        const int step = gid >> 8;
        const int kg = lane >> 4;
        const int n = lane & 15;
        const float* base = W + (size_t)(step * 32 + kg * 8) * OUT_F + ct * 16 + n;
        union { ushort u[8]; uint4 v; } pk;
        #pragma unroll
        for (int j = 0; j < 8; ++j) pk.u[j] = f2bf(base[(size_t)j * OUT_F]);
        ((uint4*)Wpk)[gid] = pk.v;
    }
}

// ---------------------------------------------------------------------------
// 1) partA: dual bucket-partition with LDS-staged write combining
//    (round-16 75.4us version) + bucket id PACKED into staged values
//    (saves 8 KB LDS -> 33.7 KB -> 4 blocks/CU, was 3).
//    stgD = (bucket<<24)|(local<<16)|src ; stgS = (bucket<<8)|src_local.
// ---------------------------------------------------------------------------
__global__ __launch_bounds__(512) void partA_kernel(const int* __restrict__ src,
                                                    const int* __restrict__ dst,
                                                    int* __restrict__ bcntD,
                                                    int* __restrict__ bcntS,
                                                    uint* __restrict__ pairsD,
                                                    ushort* __restrict__ srcloc) {
    __shared__ int2 ed[EPB];              // 16 KB  (dst, src)
    __shared__ uint stgD[EPB];            // 8 KB   staged pairs (bucket in b24-31)
    __shared__ ushort stgS[EPB];          // 4 KB   staged (bucket<<8)|local
    __shared__ int lcntD[256], lcntS[256];    // counts -> cursors
    __shared__ int ldofD[256], ldofS[256];    // local exclusive offsets
    __shared__ int lbaseD[NB], lbaseS[NB];    // global base offsets (in-bucket)
    __shared__ int wtotD[4], wtotS[4];
    const int tid = threadIdx.x;
    const int n4 = EPB / 4;   // 500

    for (int i = tid; i < 256; i += 512) { lcntD[i] = 0; lcntS[i] = 0; }
    __syncthreads();

    // load slice to LDS + count buckets
    const int4* t4 = (const int4*)(dst + (size_t)blockIdx.x * EPB);
    const int4* s4 = (const int4*)(src + (size_t)blockIdx.x * EPB);
    for (int i = tid; i < n4; i += 512) {
        const int4 d = t4[i];
        const int4 s = s4[i];
        ed[4 * i + 0] = (int2){d.x, s.x};
        ed[4 * i + 1] = (int2){d.y, s.y};
        ed[4 * i + 2] = (int2){d.z, s.z};
        ed[4 * i + 3] = (int2){d.w, s.w};
        atomicAdd(&lcntD[d.x >> 8], 1); atomicAdd(&lcntS[s.x >> 8], 1);
        atomicAdd(&lcntD[d.y >> 8], 1); atomicAdd(&lcntS[s.y >> 8], 1);
        atomicAdd(&lcntD[d.z >> 8], 1); atomicAdd(&lcntS[s.z >> 8], 1);
        atomicAdd(&lcntD[d.w >> 8], 1); atomicAdd(&lcntS[s.w >> 8], 1);
    }
    __syncthreads();

    // reserve global bucket regions
    for (int i = tid; i < NB; i += 512) {
        const int cD = lcntD[i];
        lbaseD[i] = cD ? atomicAdd(&bcntD[i], cD) : 0;
        const int cS = lcntS[i];
        lbaseS[i] = cS ? atomicAdd(&bcntS[i], cS) : 0;
    }

    // block exclusive scan of both count arrays (waves 0-3)
    if (tid < 256) {
        const int lane = tid & 63;
        const int wave = tid >> 6;
        const int vD = lcntD[tid], vS = lcntS[tid];
        int iD = vD, iS = vS;
        #pragma unroll
        for (int d = 1; d < 64; d <<= 1) {
            const int uD = __shfl_up(iD, d, 64);
            const int uS = __shfl_up(iS, d, 64);
            if (lane >= d) { iD += uD; iS += uS; }
        }
        if (lane == 63) { wtotD[wave] = iD; wtotS[wave] = iS; }
        ldofD[tid] = iD - vD;
        ldofS[tid] = iS - vS;
    }
    __syncthreads();
    if (tid < 256) {
        const int wave = tid >> 6;
        int woD = 0, woS = 0;
        #pragma unroll
        for (int w = 0; w < 4; ++w)
            if (w < wave) { woD += wtotD[w]; woS += wtotS[w]; }
        ldofD[tid] += woD;
        ldofS[tid] += woS;
        lcntD[tid] = 0;      // reuse as cursors
        lcntS[tid] = 0;
    }
    __syncthreads();

    // place into LDS staging, sorted by bucket (bucket id packed in value)
    for (int i = tid; i < EPB; i += 512) {
        const int2 e = ed[i];
        int bx = e.x >> 8;
        int pos = atomicAdd(&lcntD[bx], 1);
        stgD[ldofD[bx] + pos] =
            ((uint)bx << 24) | ((uint)(e.x & 255) << 16) | (uint)e.y;
        bx = e.y >> 8;
        pos = atomicAdd(&lcntS[bx], 1);
        stgS[ldofS[bx] + pos] = (ushort)((bx << 8) | (e.y & 255));
    }
    __syncthreads();

    // write out in staging order: consecutive lanes -> consecutive dests
    for (int i = tid; i < EPB; i += 512) {
        const uint pv = stgD[i];
        const int bD = (int)(pv >> 24);
        pairsD[(size_t)bD * CAP + lbaseD[bD] + (i - ldofD[bD])] = pv & 0xFFFFFFu;
        const ushort sv = stgS[i];
        const int bS = sv >> 8;
        srcloc[(size_t)bS * CAP + lbaseS[bS] + (i - ldofS[bS])] = (ushort)(sv & 255u);
    }
}

// ---------------------------------------------------------------------------
// 2) bucket: fused degB + partB, 1024 threads (round-16, kept).
// ---------------------------------------------------------------------------
__global__ __launch_bounds__(1024) void bucket_kernel(const ushort* __restrict__ srcloc,
                                                      const int* __restrict__ bcntS,
                                                      float* __restrict__ normS,
                                                      const uint* __restrict__ pairsD,
                                                      const int* __restrict__ bcntD,
                                                      int* __restrict__ ptr,
                                                      int* __restrict__ indeg,
                                                      ushort* __restrict__ sorted_src) {
    __shared__ int cnt[BKT];
    __shared__ int loff[BKT];
    __shared__ int wtot[4];
    const int bb = blockIdx.x;
    const int tid = threadIdx.x;
    const int node = bb * BKT + tid;   // valid meaning only for tid<256

    // --- phase 1: out-degree -> normS ---
    if (tid < BKT) cnt[tid] = 0;
    __syncthreads();
    const int nS = bcntS[bb];
    const ushort* sp = srcloc + (size_t)bb * CAP;
    for (int i = tid; i < nS; i += 1024) atomicAdd(&cnt[sp[i]], 1);
    __syncthreads();
    if (tid < BKT && node < N_NODES)
        normS[node] = rsqrtf(fmaxf((float)cnt[tid], 1.0f));
    __syncthreads();

    // --- phase 2: dst sort ---
    if (tid < BKT) cnt[tid] = 0;
    __syncthreads();
    const int nD = bcntD[bb];
    const uint* pb = pairsD + (size_t)bb * CAP;
    for (int i = tid; i < nD; i += 1024) atomicAdd(&cnt[(pb[i] >> 16) & 255u], 1);
    __syncthreads();

    // scan on waves 0-3
    if (tid < BKT) {
        const int lane = tid & 63;
        const int wave = tid >> 6;
        const int v = cnt[tid];
        int incl = v;
        #pragma unroll
        for (int d = 1; d < 64; d <<= 1) {
            int u = __shfl_up(incl, d, 64);
            if (lane >= d) incl += u;
        }
        if (lane == 63) wtot[wave] = incl;
        loff[tid] = incl - v;            // temp: intra-wave exclusive
    }
    __syncthreads();
    if (tid < BKT) {
        const int wave = tid >> 6;
        int woff = 0;
        #pragma unroll
        for (int w = 0; w < 4; ++w)
            if (w < wave) woff += wtot[w];
        const int ex = woff + loff[tid];
        loff[tid] = ex;
        const int v = cnt[tid];
        cnt[tid] = 0;                    // reuse as per-local cursor
        if (node < N_NODES) { ptr[node] = bb * CAP + ex; indeg[node] = v; }
    }
    __syncthreads();

    for (int i = tid; i < nD; i += 1024) {
        const uint p = pb[i];
        const int local = (int)((p >> 16) & 255u);
        const int pos = atomicAdd(&cnt[local], 1);
        sorted_src[(size_t)bb * CAP + loff[local] + pos] = (ushort)(p & 0xFFFFu);
    }
}

// ---------------------------------------------------------------------------
// 3) gemm: h_raw = bf16(feat @ W) via MFMA, LDS-staged A, BM=32 (round-16).
// ---------------------------------------------------------------------------
__global__ __launch_bounds__(256) void gemm_kernel(const float* __restrict__ feat,
                                                   const ushort* __restrict__ Wpk,
                                                   ushort* __restrict__ h) {
    __shared__ float ftile[GEMM_BM * IN_F];   // 32 KB
    const int tid = threadIdx.x;
    const int lane = tid & 63;
    const int wave = tid >> 6;
    const int m = lane & 15;
    const int g = lane >> 4;
    const int rowBase = blockIdx.x * GEMM_BM;
    const char* fb = (const char*)feat;

    #pragma unroll
    for (int it = 0; it < 8; ++it) {
        const int R = it * 4 + wave;                        // tile row 0..31
        const int off = (lane * 16) ^ ((R & 7) << 4);       // swizzled src chunk
        int grow = rowBase + R;
        if (grow >= N_NODES) grow = N_NODES - 1;            // clamp (dup row)
        __builtin_amdgcn_global_load_lds(
            (const __attribute__((address_space(1))) void*)(fb + ((size_t)grow << 10) + off),
            (__attribute__((address_space(3))) void*)((char*)ftile + it * 4096 + wave * 1024),
            16, 0, 0);
    }
    __syncthreads();

    const int rowHalf = wave & 1;              // 0/1: rows 0-15 / 16-31
    const int colHalf = wave >> 1;             // 0/1: cols 0-31 / 32-63

    f32x4 acc[2];
    acc[0] = (f32x4){0.f, 0.f, 0.f, 0.f};
    acc[1] = (f32x4){0.f, 0.f, 0.f, 0.f};

    const int Rr = rowHalf * 16 + m;           // A-frag row within tile
    const int swz = (Rr & 7) << 4;
    const char* rowb = (const char*)ftile + (Rr << 10);
    const bf16x8* wp = (const bf16x8*)Wpk;

    #pragma unroll
    for (int step = 0; step < 8; ++step) {
        const int kb = step * 128 + g * 32;
        const float4 a0 = *(const float4*)(rowb + (kb ^ swz));
        const float4 a1 = *(const float4*)(rowb + ((kb + 16) ^ swz));
        bf16x8 aa;
        aa[0] = (short)f2bf(a0.x); aa[1] = (short)f2bf(a0.y);
        aa[2] = (short)f2bf(a0.z); aa[3] = (short)f2bf(a0.w);
        aa[4] = (short)f2bf(a1.x); aa[5] = (short)f2bf(a1.y);
        aa[6] = (short)f2bf(a1.z); aa[7] = (short)f2bf(a1.w);
        #pragma unroll
        for (int ct = 0; ct < 2; ++ct)
            acc[ct] = __builtin_amdgcn_mfma_f32_16x16x32_bf16(
                aa, wp[(step * 4 + colHalf * 2 + ct) * 64 + lane], acc[ct], 0, 0, 0);
    }

    // C-frag: col = colHalf*32 + ct*16 + m, row = rowBase + rowHalf*16 + g*4 + j
    #pragma unroll
    for (int j = 0; j < 4; ++j) {
        const int row = rowBase + rowHalf * 16 + g * 4 + j;
        if (row < N_NODES) {
            #pragma unroll
            for (int ct = 0; ct < 2; ++ct)
                h[(size_t)row * OUT_F + colHalf * 32 + ct * 16 + m] = f2bf(acc[ct][j]);
        }
    }
}

// ---------------------------------------------------------------------------
// 4) Gather + epilogue: one wave per dst node, QUARTER-wave per edge
//    (16 lanes x 8 B = full 128 B h-row), 4 edges/iter (round-16, kept).
// ---------------------------------------------------------------------------
__global__ __launch_bounds__(256) void gather_kernel(const int* __restrict__ ptr,
                                                     const int* __restrict__ indeg,
                                                     const ushort* __restrict__ sorted_src,
                                                     const float* __restrict__ normS,
                                                     const ushort* __restrict__ h,
                                                     const float* __restrict__ b,
                                                     float* __restrict__ out) {
    const int lane = threadIdx.x & 63;
    const int q = lane & 15;           // col group: cols q*4 .. q*4+3
    const int g = lane >> 4;           // edge slot 0..3
    int nid = (int)((blockIdx.x * (size_t)blockDim.x + threadIdx.x) >> 6);
    if (nid >= N_NODES) return;
    nid = __builtin_amdgcn_readfirstlane(nid);

    const int beg = ptr[nid];
    const int deg = indeg[nid];

    float a0 = 0.f, a1 = 0.f, a2 = 0.f, a3 = 0.f;
    const int nfull = deg >> 2;
    int e = beg + g;
    #pragma unroll 4
    for (int i = 0; i < nfull; ++i) {
        const int s = (int)sorted_src[e];
        e += 4;
        const float ns = normS[s];
        const uint2 v = *(const uint2*)(h + (size_t)s * OUT_F + q * 4);
        a0 = fmaf(ns, bf_lo(v.x), a0); a1 = fmaf(ns, bf_hi(v.x), a1);
        a2 = fmaf(ns, bf_lo(v.y), a2); a3 = fmaf(ns, bf_hi(v.y), a3);
    }
    const int rem = deg & 3;
    if (g < rem) {
        const int s = (int)sorted_src[beg + (deg & ~3) + g];
        const float ns = normS[s];
        const uint2 v = *(const uint2*)(h + (size_t)s * OUT_F + q * 4);
        a0 = fmaf(ns, bf_lo(v.x), a0); a1 = fmaf(ns, bf_hi(v.x), a1);
        a2 = fmaf(ns, bf_lo(v.y), a2); a3 = fmaf(ns, bf_hi(v.y), a3);
    }
    a0 += __shfl_xor(a0, 16, 64); a1 += __shfl_xor(a1, 16, 64);
    a2 += __shfl_xor(a2, 16, 64); a3 += __shfl_xor(a3, 16, 64);
    a0 += __shfl_xor(a0, 32, 64); a1 += __shfl_xor(a1, 32, 64);
    a2 += __shfl_xor(a2, 32, 64); a3 += __shfl_xor(a3, 32, 64);

    if (g == 0) {
        const float norm = rsqrtf(fmaxf((float)deg, 1.0f));
        const float4 bb = *(const float4*)(b + q * 4);
        float4 o;
        o.x = 1.0f / (1.0f + expf(-(a0 * norm + bb.x)));
        o.y = 1.0f / (1.0f + expf(-(a1 * norm + bb.y)));
        o.z = 1.0f / (1.0f + expf(-(a2 * norm + bb.z)));
        o.w = 1.0f / (1.0f + expf(-(a3 * norm + bb.w)));
        *(float4*)(out + (size_t)nid * OUT_F + q * 4) = o;
    }
}

// ---------------------------------------------------------------------------
extern "C" void kernel_launch(void* const* d_in, const int* in_sizes, int n_in,
                              void* d_out, int out_size, void* d_ws, size_t ws_size,
                              hipStream_t stream) {
    const float* feat = (const float*)d_in[0];
    const int* src    = (const int*)d_in[1];
    const int* dst    = (const int*)d_in[2];
    const float* W    = (const float*)d_in[3];
    const float* b    = (const float*)d_in[4];
    float* out = (float*)d_out;

    char* ws = (char*)d_ws;
    size_t off = 0;
    ushort* h = (ushort*)(ws + off);        off += (size_t)N_NODES * OUT_F * 2;  // 6.4 MB
    float* normS = (float*)(ws + off);      off += (size_t)N_NODES * 4;          // 200 KB
    int* indeg = (int*)(ws + off);          off += (size_t)N_NODES * 4;          // 200 KB
    int* ptr = (int*)(ws + off);            off += (size_t)N_NODES * 4;          // 200 KB
    int* bcnt = (int*)(ws + off);           off += (size_t)2 * NB * 4;           // bcntD|bcntS
    ushort* Wpk = (ushort*)(ws + off);      off += (size_t)IN_F * OUT_F * 2;     // 32 KB
    uint* pairsD = (uint*)(ws + off);       off += (size_t)NB * CAP * 4;         // 4.8 MB
    ushort* srcloc = (ushort*)(ws + off);   off += (size_t)NB * CAP * 2;         // 2.4 MB
    ushort* sorted_src = (ushort*)(ws + off); off += (size_t)NB * CAP * 2;       // 2.4 MB
    int* bcntD = bcnt;
    int* bcntS = bcnt + NB;

    prep_kernel<<<9, 256, 0, stream>>>(bcnt, W, Wpk);

    partA_kernel<<<PARTA_BLOCKS, 512, 0, stream>>>(src, dst, bcntD, bcntS, pairsD, srcloc);

    bucket_kernel<<<NB, 1024, 0, stream>>>(srcloc, bcntS, normS,
                                           pairsD, bcntD, ptr, indeg, sorted_src);

    gemm_kernel<<<(N_NODES + GEMM_BM - 1) / GEMM_BM, 256, 0, stream>>>(feat, Wpk, h);

    gather_kernel<<<(N_NODES * 64 + 255) / 256, 256, 0, stream>>>(
        ptr, indeg, sorted_src, normS, h, b, out);
}

// Round 20
// 74.717 us; speedup vs baseline: 1.0628x; 1.0010x over previous
//
#include <hip/hip_runtime.h>
#include <hip/hip_bf16.h>
#include <math.h>

#define N_NODES 50000
#define N_EDGES 800000
#define IN_F 256
#define OUT_F 64

#define BKT 256            // nodes per bucket
#define NB 196             // ceil(50000/256)
#define CAP 6144           // fixed per-bucket capacity (mean 4096, sigma 64)
#define PARTA_BLOCKS 400   // 800000/400 = 2000 edges/block
#define EPB (N_EDGES / PARTA_BLOCKS)   // 2000
#define GEMM_BM 32         // 32 KB LDS -> 4 blocks/CU

typedef __attribute__((ext_vector_type(8))) short bf16x8;
typedef __attribute__((ext_vector_type(4))) float f32x4;

__device__ __forceinline__ ushort f2bf(float x) {
    __hip_bfloat16 b = __float2bfloat16(x);   // RNE
    return *reinterpret_cast<ushort*>(&b);
}
__device__ __forceinline__ float bf_lo(uint v) { return __uint_as_float(v << 16); }
__device__ __forceinline__ float bf_hi(uint v) { return __uint_as_float(v & 0xffff0000u); }

// ---------------------------------------------------------------------------
// 0) prep: block 0 zeros bcntD+bcntS; blocks 1..8 pack W into bf16 MFMA
//    B-frag layout.
// ---------------------------------------------------------------------------
__global__ __launch_bounds__(256) void prep_kernel(int* __restrict__ bcnt,
                                                   const float* __restrict__ W,
                                                   ushort* __restrict__ Wpk) {
    const int tid = threadIdx.x;
    if (blockIdx.x == 0) {
        for (int i = tid; i < 2 * NB; i += 256) bcnt[i] = 0;
    } else {
        const int gid = (blockIdx.x - 1) * 256 + tid;   // 0..2047
        const int lane = gid & 63;
        const int ct = (gid >> 6) & 3;
        const int step = gid >> 8;
        const int kg = lane >> 4;
        const int n = lane & 15;
        const float* base = W + (size_t)(step * 32 + kg * 8) * OUT_F + ct * 16 + n;
        union { ushort u[8]; uint4 v; } pk;
        #pragma unroll
        for (int j = 0; j < 8; ++j) pk.u[j] = f2bf(base[(size_t)j * OUT_F]);
        ((uint4*)Wpk)[gid] = pk.v;
    }
}

// ---------------------------------------------------------------------------
// 1) partA: dual bucket-partition, LDS-staged write combining, bucket id
//    packed into staged values (round-19, kept — 74.8us config).
// ---------------------------------------------------------------------------
__global__ __launch_bounds__(512) void partA_kernel(const int* __restrict__ src,
                                                    const int* __restrict__ dst,
                                                    int* __restrict__ bcntD,
                                                    int* __restrict__ bcntS,
                                                    uint* __restrict__ pairsD,
                                                    ushort* __restrict__ srcloc) {
    __shared__ int2 ed[EPB];              // 16 KB  (dst, src)
    __shared__ uint stgD[EPB];            // 8 KB   staged pairs (bucket in b24-31)
    __shared__ ushort stgS[EPB];          // 4 KB   staged (bucket<<8)|local
    __shared__ int lcntD[256], lcntS[256];    // counts -> cursors
    __shared__ int ldofD[256], ldofS[256];    // local exclusive offsets
    __shared__ int lbaseD[NB], lbaseS[NB];    // global base offsets (in-bucket)
    __shared__ int wtotD[4], wtotS[4];
    const int tid = threadIdx.x;
    const int n4 = EPB / 4;   // 500

    for (int i = tid; i < 256; i += 512) { lcntD[i] = 0; lcntS[i] = 0; }
    __syncthreads();

    // load slice to LDS + count buckets
    const int4* t4 = (const int4*)(dst + (size_t)blockIdx.x * EPB);
    const int4* s4 = (const int4*)(src + (size_t)blockIdx.x * EPB);
    for (int i = tid; i < n4; i += 512) {
        const int4 d = t4[i];
        const int4 s = s4[i];
        ed[4 * i + 0] = (int2){d.x, s.x};
        ed[4 * i + 1] = (int2){d.y, s.y};
        ed[4 * i + 2] = (int2){d.z, s.z};
        ed[4 * i + 3] = (int2){d.w, s.w};
        atomicAdd(&lcntD[d.x >> 8], 1); atomicAdd(&lcntS[s.x >> 8], 1);
        atomicAdd(&lcntD[d.y >> 8], 1); atomicAdd(&lcntS[s.y >> 8], 1);
        atomicAdd(&lcntD[d.z >> 8], 1); atomicAdd(&lcntS[s.z >> 8], 1);
        atomicAdd(&lcntD[d.w >> 8], 1); atomicAdd(&lcntS[s.w >> 8], 1);
    }
    __syncthreads();

    // reserve global bucket regions
    for (int i = tid; i < NB; i += 512) {
        const int cD = lcntD[i];
        lbaseD[i] = cD ? atomicAdd(&bcntD[i], cD) : 0;
        const int cS = lcntS[i];
        lbaseS[i] = cS ? atomicAdd(&bcntS[i], cS) : 0;
    }

    // block exclusive scan of both count arrays (waves 0-3)
    if (tid < 256) {
        const int lane = tid & 63;
        const int wave = tid >> 6;
        const int vD = lcntD[tid], vS = lcntS[tid];
        int iD = vD, iS = vS;
        #pragma unroll
        for (int d = 1; d < 64; d <<= 1) {
            const int uD = __shfl_up(iD, d, 64);
            const int uS = __shfl_up(iS, d, 64);
            if (lane >= d) { iD += uD; iS += uS; }
        }
        if (lane == 63) { wtotD[wave] = iD; wtotS[wave] = iS; }
        ldofD[tid] = iD - vD;
        ldofS[tid] = iS - vS;
    }
    __syncthreads();
    if (tid < 256) {
        const int wave = tid >> 6;
        int woD = 0, woS = 0;
        #pragma unroll
        for (int w = 0; w < 4; ++w)
            if (w < wave) { woD += wtotD[w]; woS += wtotS[w]; }
        ldofD[tid] += woD;
        ldofS[tid] += woS;
        lcntD[tid] = 0;      // reuse as cursors
        lcntS[tid] = 0;
    }
    __syncthreads();

    // place into LDS staging, sorted by bucket (bucket id packed in value)
    for (int i = tid; i < EPB; i += 512) {
        const int2 e = ed[i];
        int bx = e.x >> 8;
        int pos = atomicAdd(&lcntD[bx], 1);
        stgD[ldofD[bx] + pos] =
            ((uint)bx << 24) | ((uint)(e.x & 255) << 16) | (uint)e.y;
        bx = e.y >> 8;
        pos = atomicAdd(&lcntS[bx], 1);
        stgS[ldofS[bx] + pos] = (ushort)((bx << 8) | (e.y & 255));
    }
    __syncthreads();

    // write out in staging order: consecutive lanes -> consecutive dests
    for (int i = tid; i < EPB; i += 512) {
        const uint pv = stgD[i];
        const int bD = (int)(pv >> 24);
        pairsD[(size_t)bD * CAP + lbaseD[bD] + (i - ldofD[bD])] = pv & 0xFFFFFFu;
        const ushort sv = stgS[i];
        const int bS = sv >> 8;
        srcloc[(size_t)bS * CAP + lbaseS[bS] + (i - ldofS[bS])] = (ushort)(sv & 255u);
    }
}

// ---------------------------------------------------------------------------
// 2) bucket: fused degB + partB, 1024 threads. Phase 2 writes PACKED
//    ptrdeg = (bb*CAP + ex) | (deg << 21)   [ptr < 2^21, deg < 2^11].
// ---------------------------------------------------------------------------
__global__ __launch_bounds__(1024) void bucket_kernel(const ushort* __restrict__ srcloc,
                                                      const int* __restrict__ bcntS,
                                                      float* __restrict__ normS,
                                                      const uint* __restrict__ pairsD,
                                                      const int* __restrict__ bcntD,
                                                      uint* __restrict__ ptrdeg,
                                                      ushort* __restrict__ sorted_src) {
    __shared__ int cnt[BKT];
    __shared__ int loff[BKT];
    __shared__ int wtot[4];
    const int bb = blockIdx.x;
    const int tid = threadIdx.x;
    const int node = bb * BKT + tid;   // valid meaning only for tid<256

    // --- phase 1: out-degree -> normS ---
    if (tid < BKT) cnt[tid] = 0;
    __syncthreads();
    const int nS = bcntS[bb];
    const ushort* sp = srcloc + (size_t)bb * CAP;
    for (int i = tid; i < nS; i += 1024) atomicAdd(&cnt[sp[i]], 1);
    __syncthreads();
    if (tid < BKT && node < N_NODES)
        normS[node] = rsqrtf(fmaxf((float)cnt[tid], 1.0f));
    __syncthreads();

    // --- phase 2: dst sort ---
    if (tid < BKT) cnt[tid] = 0;
    __syncthreads();
    const int nD = bcntD[bb];
    const uint* pb = pairsD + (size_t)bb * CAP;
    for (int i = tid; i < nD; i += 1024) atomicAdd(&cnt[(pb[i] >> 16) & 255u], 1);
    __syncthreads();

    // scan on waves 0-3
    if (tid < BKT) {
        const int lane = tid & 63;
        const int wave = tid >> 6;
        const int v = cnt[tid];
        int incl = v;
        #pragma unroll
        for (int d = 1; d < 64; d <<= 1) {
            int u = __shfl_up(incl, d, 64);
            if (lane >= d) incl += u;
        }
        if (lane == 63) wtot[wave] = incl;
        loff[tid] = incl - v;            // temp: intra-wave exclusive
    }
    __syncthreads();
    if (tid < BKT) {
        const int wave = tid >> 6;
        int woff = 0;
        #pragma unroll
        for (int w = 0; w < 4; ++w)
            if (w < wave) woff += wtot[w];
        const int ex = woff + loff[tid];
        loff[tid] = ex;
        const int v = cnt[tid];
        cnt[tid] = 0;                    // reuse as per-local cursor
        if (node < N_NODES)
            ptrdeg[node] = (uint)(bb * CAP + ex) | ((uint)v << 21);
    }
    __syncthreads();

    for (int i = tid; i < nD; i += 1024) {
        const uint p = pb[i];
        const int local = (int)((p >> 16) & 255u);
        const int pos = atomicAdd(&cnt[local], 1);
        sorted_src[(size_t)bb * CAP + loff[local] + pos] = (ushort)(p & 0xFFFFu);
    }
}

// ---------------------------------------------------------------------------
// 3) gemm: h = bf16( normS * (feat @ W) ) via MFMA, LDS-staged A, BM=32.
//    normS multiply moved back here (serial stream: normS ready anyway);
//    gather's per-edge normS lookup disappears.
// ---------------------------------------------------------------------------
__global__ __launch_bounds__(256) void gemm_kernel(const float* __restrict__ feat,
                                                   const ushort* __restrict__ Wpk,
                                                   const float* __restrict__ normS,
                                                   ushort* __restrict__ h) {
    __shared__ float ftile[GEMM_BM * IN_F];   // 32 KB
    const int tid = threadIdx.x;
    const int lane = tid & 63;
    const int wave = tid >> 6;
    const int m = lane & 15;
    const int g = lane >> 4;
    const int rowBase = blockIdx.x * GEMM_BM;
    const char* fb = (const char*)feat;

    #pragma unroll
    for (int it = 0; it < 8; ++it) {
        const int R = it * 4 + wave;                        // tile row 0..31
        const int off = (lane * 16) ^ ((R & 7) << 4);       // swizzled src chunk
        int grow = rowBase + R;
        if (grow >= N_NODES) grow = N_NODES - 1;            // clamp (dup row)
        __builtin_amdgcn_global_load_lds(
            (const __attribute__((address_space(1))) void*)(fb + ((size_t)grow << 10) + off),
            (__attribute__((address_space(3))) void*)((char*)ftile + it * 4096 + wave * 1024),
            16, 0, 0);
    }
    __syncthreads();

    const int rowHalf = wave & 1;              // 0/1: rows 0-15 / 16-31
    const int colHalf = wave >> 1;             // 0/1: cols 0-31 / 32-63

    f32x4 acc[2];
    acc[0] = (f32x4){0.f, 0.f, 0.f, 0.f};
    acc[1] = (f32x4){0.f, 0.f, 0.f, 0.f};

    const int Rr = rowHalf * 16 + m;           // A-frag row within tile
    const int swz = (Rr & 7) << 4;
    const char* rowb = (const char*)ftile + (Rr << 10);
    const bf16x8* wp = (const bf16x8*)Wpk;

    #pragma unroll
    for (int step = 0; step < 8; ++step) {
        const int kb = step * 128 + g * 32;
        const float4 a0 = *(const float4*)(rowb + (kb ^ swz));
        const float4 a1 = *(const float4*)(rowb + ((kb + 16) ^ swz));
        bf16x8 aa;
        aa[0] = (short)f2bf(a0.x); aa[1] = (short)f2bf(a0.y);
        aa[2] = (short)f2bf(a0.z); aa[3] = (short)f2bf(a0.w);
        aa[4] = (short)f2bf(a1.x); aa[5] = (short)f2bf(a1.y);
        aa[6] = (short)f2bf(a1.z); aa[7] = (short)f2bf(a1.w);
        #pragma unroll
        for (int ct = 0; ct < 2; ++ct)
            acc[ct] = __builtin_amdgcn_mfma_f32_16x16x32_bf16(
                aa, wp[(step * 4 + colHalf * 2 + ct) * 64 + lane], acc[ct], 0, 0, 0);
    }

    // C-frag: col = colHalf*32 + ct*16 + m, row = rowBase + rowHalf*16 + g*4 + j
    #pragma unroll
    for (int j = 0; j < 4; ++j) {
        const int row = rowBase + rowHalf * 16 + g * 4 + j;
        if (row < N_NODES) {
            const float ns = normS[row];
            #pragma unroll
            for (int ct = 0; ct < 2; ++ct)
                h[(size_t)row * OUT_F + colHalf * 32 + ct * 16 + m] =
                    f2bf(acc[ct][j] * ns);
        }
    }
}

// ---------------------------------------------------------------------------
// 4) Gather + epilogue: one wave per dst node, quarter-wave per edge.
//    h is pre-scaled (plain adds); single packed ptrdeg load per node.
// ---------------------------------------------------------------------------
__global__ __launch_bounds__(256) void gather_kernel(const uint* __restrict__ ptrdeg,
                                                     const ushort* __restrict__ sorted_src,
                                                     const ushort* __restrict__ h,
                                                     const float* __restrict__ b,
                                                     float* __restrict__ out) {
    const int lane = threadIdx.x & 63;
    const int q = lane & 15;           // col group: cols q*4 .. q*4+3
    const int g = lane >> 4;           // edge slot 0..3
    int nid = (int)((blockIdx.x * (size_t)blockDim.x + threadIdx.x) >> 6);
    if (nid >= N_NODES) return;
    nid = __builtin_amdgcn_readfirstlane(nid);

    const uint pd = ptrdeg[nid];
    const int beg = (int)(pd & 0x1FFFFFu);
    const int deg = (int)(pd >> 21);

    float a0 = 0.f, a1 = 0.f, a2 = 0.f, a3 = 0.f;
    const int nfull = deg >> 2;
    int e = beg + g;
    #pragma unroll 4
    for (int i = 0; i < nfull; ++i) {
        const int s = (int)sorted_src[e];
        e += 4;
        const uint2 v = *(const uint2*)(h + (size_t)s * OUT_F + q * 4);
        a0 += bf_lo(v.x); a1 += bf_hi(v.x);
        a2 += bf_lo(v.y); a3 += bf_hi(v.y);
    }
    const int rem = deg & 3;
    if (g < rem) {
        const int s = (int)sorted_src[beg + (deg & ~3) + g];
        const uint2 v = *(const uint2*)(h + (size_t)s * OUT_F + q * 4);
        a0 += bf_lo(v.x); a1 += bf_hi(v.x);
        a2 += bf_lo(v.y); a3 += bf_hi(v.y);
    }
    a0 += __shfl_xor(a0, 16, 64); a1 += __shfl_xor(a1, 16, 64);
    a2 += __shfl_xor(a2, 16, 64); a3 += __shfl_xor(a3, 16, 64);
    a0 += __shfl_xor(a0, 32, 64); a1 += __shfl_xor(a1, 32, 64);
    a2 += __shfl_xor(a2, 32, 64); a3 += __shfl_xor(a3, 32, 64);

    if (g == 0) {
        const float norm = rsqrtf(fmaxf((float)deg, 1.0f));
        const float4 bb = *(const float4*)(b + q * 4);
        float4 o;
        o.x = 1.0f / (1.0f + expf(-(a0 * norm + bb.x)));
        o.y = 1.0f / (1.0f + expf(-(a1 * norm + bb.y)));
        o.z = 1.0f / (1.0f + expf(-(a2 * norm + bb.z)));
        o.w = 1.0f / (1.0f + expf(-(a3 * norm + bb.w)));
        *(float4*)(out + (size_t)nid * OUT_F + q * 4) = o;
    }
}

// ---------------------------------------------------------------------------
extern "C" void kernel_launch(void* const* d_in, const int* in_sizes, int n_in,
                              void* d_out, int out_size, void* d_ws, size_t ws_size,
                              hipStream_t stream) {
    const float* feat = (const float*)d_in[0];
    const int* src    = (const int*)d_in[1];
    const int* dst    = (const int*)d_in[2];
    const float* W    = (const float*)d_in[3];
    const float* b    = (const float*)d_in[4];
    float* out = (float*)d_out;

    char* ws = (char*)d_ws;
    size_t off = 0;
    ushort* h = (ushort*)(ws + off);        off += (size_t)N_NODES * OUT_F * 2;  // 6.4 MB
    float* normS = (float*)(ws + off);      off += (size_t)N_NODES * 4;          // 200 KB
    uint* ptrdeg = (uint*)(ws + off);       off += (size_t)N_NODES * 4;          // 200 KB
    int* bcnt = (int*)(ws + off);           off += (size_t)2 * NB * 4;           // bcntD|bcntS
    ushort* Wpk = (ushort*)(ws + off);      off += (size_t)IN_F * OUT_F * 2;     // 32 KB
    uint* pairsD = (uint*)(ws + off);       off += (size_t)NB * CAP * 4;         // 4.8 MB
    ushort* srcloc = (ushort*)(ws + off);   off += (size_t)NB * CAP * 2;         // 2.4 MB
    ushort* sorted_src = (ushort*)(ws + off); off += (size_t)NB * CAP * 2;       // 2.4 MB
    int* bcntD = bcnt;
    int* bcntS = bcnt + NB;

    prep_kernel<<<9, 256, 0, stream>>>(bcnt, W, Wpk);

    partA_kernel<<<PARTA_BLOCKS, 512, 0, stream>>>(src, dst, bcntD, bcntS, pairsD, srcloc);

    bucket_kernel<<<NB, 1024, 0, stream>>>(srcloc, bcntS, normS,
                                           pairsD, bcntD, ptrdeg, sorted_src);

    gemm_kernel<<<(N_NODES + GEMM_BM - 1) / GEMM_BM, 256, 0, stream>>>(feat, Wpk, normS, h);

    gather_kernel<<<(N_NODES * 64 + 255) / 256, 256, 0, stream>>>(
        ptrdeg, sorted_src, h, b, out);
}

// Round 21
// 68.151 us; speedup vs baseline: 1.1653x; 1.0964x over previous
//
#include <hip/hip_runtime.h>
#include <hip/hip_bf16.h>
#include <math.h>

#define N_NODES 50000
#define N_EDGES 800000
#define IN_F 256
#define OUT_F 64

#define BKT 256            // nodes per bucket
#define NB 196             // ceil(50000/256)
#define CAP 6144           // fixed per-bucket capacity (mean 4096, sigma 64)
#define PARTA_BLOCKS 400   // 800000/400 = 2000 edges/block
#define EPB (N_EDGES / PARTA_BLOCKS)   // 2000
#define GEMM_BM 32
#define GEMM_BLOCKS 782    // ceil(ceil(50000/32)/2) two tiles per 512-thr block

typedef __attribute__((ext_vector_type(8))) short bf16x8;
typedef __attribute__((ext_vector_type(4))) float f32x4;

__device__ __forceinline__ ushort f2bf(float x) {
    __hip_bfloat16 b = __float2bfloat16(x);   // RNE
    return *reinterpret_cast<ushort*>(&b);
}
__device__ __forceinline__ float bf_lo(uint v) { return __uint_as_float(v << 16); }
__device__ __forceinline__ float bf_hi(uint v) { return __uint_as_float(v & 0xffff0000u); }

// ---------------------------------------------------------------------------
// 0) prep: block 0 zeros bcntD+bcntS; blocks 1..8 pack W into bf16 MFMA
//    B-frag layout.
// ---------------------------------------------------------------------------
__global__ __launch_bounds__(256) void prep_kernel(int* __restrict__ bcnt,
                                                   const float* __restrict__ W,
                                                   ushort* __restrict__ Wpk) {
    const int tid = threadIdx.x;
    if (blockIdx.x == 0) {
        for (int i = tid; i < 2 * NB; i += 256) bcnt[i] = 0;
    } else {
        const int gid = (blockIdx.x - 1) * 256 + tid;   // 0..2047
        const int lane = gid & 63;
        const int ct = (gid >> 6) & 3;
        const int step = gid >> 8;
        const int kg = lane >> 4;
        const int n = lane & 15;
        const float* base = W + (size_t)(step * 32 + kg * 8) * OUT_F + ct * 16 + n;
        union { ushort u[8]; uint4 v; } pk;
        #pragma unroll
        for (int j = 0; j < 8; ++j) pk.u[j] = f2bf(base[(size_t)j * OUT_F]);
        ((uint4*)Wpk)[gid] = pk.v;
    }
}

// ---------------------------------------------------------------------------
// 1) fused: partA (LDS-atomic/latency-bound) overlapped with gemm
//    (BW/MFMA-bound) — disjoint resources, independent data (gemm writes
//    RAW h; normS applied in gather). 64 KB carved LDS union.
//    Roles: bi<800: odd=partA(bi>>1), even=gemm(bi>>1); bi>=800: gemm(bi-400).
//    gemm role = two independent BM=32 tiles (two 256-thread halves).
// ---------------------------------------------------------------------------
__global__ __launch_bounds__(512) void fused_kernel(const int* __restrict__ src,
                                                    const int* __restrict__ dst,
                                                    int* __restrict__ bcntD,
                                                    int* __restrict__ bcntS,
                                                    uint* __restrict__ pairsD,
                                                    ushort* __restrict__ srcloc,
                                                    const float* __restrict__ feat,
                                                    const ushort* __restrict__ Wpk,
                                                    ushort* __restrict__ h) {
    __shared__ __align__(16) char smem[65536];
    const int bi = blockIdx.x;
    const int tid = threadIdx.x;

    if (bi < 2 * PARTA_BLOCKS && (bi & 1)) {
        // ---------------- partA role (round-19/20 code, carved LDS) --------
        int2* ed      = (int2*)smem;                    // 16000
        uint* stgD    = (uint*)(smem + 16000);          //  8000
        int* lcntD    = (int*)(smem + 24000);
        int* lcntS    = (int*)(smem + 25024);
        int* ldofD    = (int*)(smem + 26048);
        int* ldofS    = (int*)(smem + 27072);
        int* lbaseD   = (int*)(smem + 28096);
        int* lbaseS   = (int*)(smem + 28880);
        int* wtotD    = (int*)(smem + 29664);
        int* wtotS    = (int*)(smem + 29680);
        ushort* stgS  = (ushort*)(smem + 29696);        //  4000 -> 33696
        const int id = bi >> 1;
        const int n4 = EPB / 4;   // 500

        for (int i = tid; i < 256; i += 512) { lcntD[i] = 0; lcntS[i] = 0; }
        __syncthreads();

        const int4* t4 = (const int4*)(dst + (size_t)id * EPB);
        const int4* s4 = (const int4*)(src + (size_t)id * EPB);
        for (int i = tid; i < n4; i += 512) {
            const int4 d = t4[i];
            const int4 s = s4[i];
            ed[4 * i + 0] = (int2){d.x, s.x};
            ed[4 * i + 1] = (int2){d.y, s.y};
            ed[4 * i + 2] = (int2){d.z, s.z};
            ed[4 * i + 3] = (int2){d.w, s.w};
            atomicAdd(&lcntD[d.x >> 8], 1); atomicAdd(&lcntS[s.x >> 8], 1);
            atomicAdd(&lcntD[d.y >> 8], 1); atomicAdd(&lcntS[s.y >> 8], 1);
            atomicAdd(&lcntD[d.z >> 8], 1); atomicAdd(&lcntS[s.z >> 8], 1);
            atomicAdd(&lcntD[d.w >> 8], 1); atomicAdd(&lcntS[s.w >> 8], 1);
        }
        __syncthreads();

        for (int i = tid; i < NB; i += 512) {
            const int cD = lcntD[i];
            lbaseD[i] = cD ? atomicAdd(&bcntD[i], cD) : 0;
            const int cS = lcntS[i];
            lbaseS[i] = cS ? atomicAdd(&bcntS[i], cS) : 0;
        }

        if (tid < 256) {
            const int lane = tid & 63;
            const int wave = tid >> 6;
            const int vD = lcntD[tid], vS = lcntS[tid];
            int iD = vD, iS = vS;
            #pragma unroll
            for (int d = 1; d < 64; d <<= 1) {
                const int uD = __shfl_up(iD, d, 64);
                const int uS = __shfl_up(iS, d, 64);
                if (lane >= d) { iD += uD; iS += uS; }
            }
            if (lane == 63) { wtotD[wave] = iD; wtotS[wave] = iS; }
            ldofD[tid] = iD - vD;
            ldofS[tid] = iS - vS;
        }
        __syncthreads();
        if (tid < 256) {
            const int wave = tid >> 6;
            int woD = 0, woS = 0;
            #pragma unroll
            for (int w = 0; w < 4; ++w)
                if (w < wave) { woD += wtotD[w]; woS += wtotS[w]; }
            ldofD[tid] += woD;
            ldofS[tid] += woS;
            lcntD[tid] = 0;
            lcntS[tid] = 0;
        }
        __syncthreads();

        for (int i = tid; i < EPB; i += 512) {
            const int2 e = ed[i];
            int bx = e.x >> 8;
            int pos = atomicAdd(&lcntD[bx], 1);
            stgD[ldofD[bx] + pos] =
                ((uint)bx << 24) | ((uint)(e.x & 255) << 16) | (uint)e.y;
            bx = e.y >> 8;
            pos = atomicAdd(&lcntS[bx], 1);
            stgS[ldofS[bx] + pos] = (ushort)((bx << 8) | (e.y & 255));
        }
        __syncthreads();

        for (int i = tid; i < EPB; i += 512) {
            const uint pv = stgD[i];
            const int bD = (int)(pv >> 24);
            pairsD[(size_t)bD * CAP + lbaseD[bD] + (i - ldofD[bD])] = pv & 0xFFFFFFu;
            const ushort sv = stgS[i];
            const int bS = sv >> 8;
            srcloc[(size_t)bS * CAP + lbaseS[bS] + (i - ldofS[bS])] = (ushort)(sv & 255u);
        }
    } else {
        // ---------------- gemm role: two BM=32 tiles ------------------------
        const int id = (bi < 2 * PARTA_BLOCKS) ? (bi >> 1) : (bi - PARTA_BLOCKS);
        const int half = tid >> 8;           // 0/1: which tile
        const int t = tid & 255;
        const int lane = t & 63;
        const int wave = t >> 6;             // 0..3 within half
        const int m = lane & 15;
        const int g = lane >> 4;
        const int rowBase = (id * 2 + half) * GEMM_BM;
        float* ftile = (float*)(smem + (size_t)half * 32768);
        const char* fb = (const char*)feat;

        #pragma unroll
        for (int it = 0; it < 8; ++it) {
            const int R = it * 4 + wave;                  // tile row 0..31
            const int off = (lane * 16) ^ ((R & 7) << 4); // swizzled src chunk
            int grow = rowBase + R;
            if (grow >= N_NODES) grow = N_NODES - 1;      // clamp (dup row)
            __builtin_amdgcn_global_load_lds(
                (const __attribute__((address_space(1))) void*)(fb + ((size_t)grow << 10) + off),
                (__attribute__((address_space(3))) void*)((char*)ftile + it * 4096 + wave * 1024),
                16, 0, 0);
        }
        __syncthreads();

        const int rowHalf = wave & 1;
        const int colHalf = wave >> 1;

        f32x4 acc[2];
        acc[0] = (f32x4){0.f, 0.f, 0.f, 0.f};
        acc[1] = (f32x4){0.f, 0.f, 0.f, 0.f};

        const int Rr = rowHalf * 16 + m;
        const int swz = (Rr & 7) << 4;
        const char* rowb = (const char*)ftile + (Rr << 10);
        const bf16x8* wp = (const bf16x8*)Wpk;

        #pragma unroll
        for (int step = 0; step < 8; ++step) {
            const int kb = step * 128 + g * 32;
            const float4 a0 = *(const float4*)(rowb + (kb ^ swz));
            const float4 a1 = *(const float4*)(rowb + ((kb + 16) ^ swz));
            bf16x8 aa;
            aa[0] = (short)f2bf(a0.x); aa[1] = (short)f2bf(a0.y);
            aa[2] = (short)f2bf(a0.z); aa[3] = (short)f2bf(a0.w);
            aa[4] = (short)f2bf(a1.x); aa[5] = (short)f2bf(a1.y);
            aa[6] = (short)f2bf(a1.z); aa[7] = (short)f2bf(a1.w);
            #pragma unroll
            for (int ct = 0; ct < 2; ++ct)
                acc[ct] = __builtin_amdgcn_mfma_f32_16x16x32_bf16(
                    aa, wp[(step * 4 + colHalf * 2 + ct) * 64 + lane], acc[ct], 0, 0, 0);
        }

        #pragma unroll
        for (int j = 0; j < 4; ++j) {
            const int row = rowBase + rowHalf * 16 + g * 4 + j;
            if (row < N_NODES) {
                #pragma unroll
                for (int ct = 0; ct < 2; ++ct)
                    h[(size_t)row * OUT_F + colHalf * 32 + ct * 16 + m] = f2bf(acc[ct][j]);
            }
        }
    }
}

// ---------------------------------------------------------------------------
// 2) bucket: fused degB + partB, 1024 threads; writes normS + packed ptrdeg.
// ---------------------------------------------------------------------------
__global__ __launch_bounds__(1024) void bucket_kernel(const ushort* __restrict__ srcloc,
                                                      const int* __restrict__ bcntS,
                                                      float* __restrict__ normS,
                                                      const uint* __restrict__ pairsD,
                                                      const int* __restrict__ bcntD,
                                                      uint* __restrict__ ptrdeg,
                                                      ushort* __restrict__ sorted_src) {
    __shared__ int cnt[BKT];
    __shared__ int loff[BKT];
    __shared__ int wtot[4];
    const int bb = blockIdx.x;
    const int tid = threadIdx.x;
    const int node = bb * BKT + tid;   // valid meaning only for tid<256

    // --- phase 1: out-degree -> normS ---
    if (tid < BKT) cnt[tid] = 0;
    __syncthreads();
    const int nS = bcntS[bb];
    const ushort* sp = srcloc + (size_t)bb * CAP;
    for (int i = tid; i < nS; i += 1024) atomicAdd(&cnt[sp[i]], 1);
    __syncthreads();
    if (tid < BKT && node < N_NODES)
        normS[node] = rsqrtf(fmaxf((float)cnt[tid], 1.0f));
    __syncthreads();

    // --- phase 2: dst sort ---
    if (tid < BKT) cnt[tid] = 0;
    __syncthreads();
    const int nD = bcntD[bb];
    const uint* pb = pairsD + (size_t)bb * CAP;
    for (int i = tid; i < nD; i += 1024) atomicAdd(&cnt[(pb[i] >> 16) & 255u], 1);
    __syncthreads();

    // scan on waves 0-3
    if (tid < BKT) {
        const int lane = tid & 63;
        const int wave = tid >> 6;
        const int v = cnt[tid];
        int incl = v;
        #pragma unroll
        for (int d = 1; d < 64; d <<= 1) {
            int u = __shfl_up(incl, d, 64);
            if (lane >= d) incl += u;
        }
        if (lane == 63) wtot[wave] = incl;
        loff[tid] = incl - v;            // temp: intra-wave exclusive
    }
    __syncthreads();
    if (tid < BKT) {
        const int wave = tid >> 6;
        int woff = 0;
        #pragma unroll
        for (int w = 0; w < 4; ++w)
            if (w < wave) woff += wtot[w];
        const int ex = woff + loff[tid];
        loff[tid] = ex;
        const int v = cnt[tid];
        cnt[tid] = 0;                    // reuse as per-local cursor
        if (node < N_NODES)
            ptrdeg[node] = (uint)(bb * CAP + ex) | ((uint)v << 21);
    }
    __syncthreads();

    for (int i = tid; i < nD; i += 1024) {
        const uint p = pb[i];
        const int local = (int)((p >> 16) & 255u);
        const int pos = atomicAdd(&cnt[local], 1);
        sorted_src[(size_t)bb * CAP + loff[local] + pos] = (ushort)(p & 0xFFFFu);
    }
}

// ---------------------------------------------------------------------------
// 3) Gather + epilogue: one wave per dst node, quarter-wave per edge,
//    gathered rows scaled by normS[src]; packed ptrdeg.
// ---------------------------------------------------------------------------
__global__ __launch_bounds__(256) void gather_kernel(const uint* __restrict__ ptrdeg,
                                                     const ushort* __restrict__ sorted_src,
                                                     const float* __restrict__ normS,
                                                     const ushort* __restrict__ h,
                                                     const float* __restrict__ b,
                                                     float* __restrict__ out) {
    const int lane = threadIdx.x & 63;
    const int q = lane & 15;           // col group: cols q*4 .. q*4+3
    const int g = lane >> 4;           // edge slot 0..3
    int nid = (int)((blockIdx.x * (size_t)blockDim.x + threadIdx.x) >> 6);
    if (nid >= N_NODES) return;
    nid = __builtin_amdgcn_readfirstlane(nid);

    const uint pd = ptrdeg[nid];
    const int beg = (int)(pd & 0x1FFFFFu);
    const int deg = (int)(pd >> 21);

    float a0 = 0.f, a1 = 0.f, a2 = 0.f, a3 = 0.f;
    const int nfull = deg >> 2;
    int e = beg + g;
    #pragma unroll 4
    for (int i = 0; i < nfull; ++i) {
        const int s = (int)sorted_src[e];
        e += 4;
        const float ns = normS[s];
        const uint2 v = *(const uint2*)(h + (size_t)s * OUT_F + q * 4);
        a0 = fmaf(ns, bf_lo(v.x), a0); a1 = fmaf(ns, bf_hi(v.x), a1);
        a2 = fmaf(ns, bf_lo(v.y), a2); a3 = fmaf(ns, bf_hi(v.y), a3);
    }
    const int rem = deg & 3;
    if (g < rem) {
        const int s = (int)sorted_src[beg + (deg & ~3) + g];
        const float ns = normS[s];
        const uint2 v = *(const uint2*)(h + (size_t)s * OUT_F + q * 4);
        a0 = fmaf(ns, bf_lo(v.x), a0); a1 = fmaf(ns, bf_hi(v.x), a1);
        a2 = fmaf(ns, bf_lo(v.y), a2); a3 = fmaf(ns, bf_hi(v.y), a3);
    }
    a0 += __shfl_xor(a0, 16, 64); a1 += __shfl_xor(a1, 16, 64);
    a2 += __shfl_xor(a2, 16, 64); a3 += __shfl_xor(a3, 16, 64);
    a0 += __shfl_xor(a0, 32, 64); a1 += __shfl_xor(a1, 32, 64);
    a2 += __shfl_xor(a2, 32, 64); a3 += __shfl_xor(a3, 32, 64);

    if (g == 0) {
        const float norm = rsqrtf(fmaxf((float)deg, 1.0f));
        const float4 bb = *(const float4*)(b + q * 4);
        float4 o;
        o.x = 1.0f / (1.0f + expf(-(a0 * norm + bb.x)));
        o.y = 1.0f / (1.0f + expf(-(a1 * norm + bb.y)));
        o.z = 1.0f / (1.0f + expf(-(a2 * norm + bb.z)));
        o.w = 1.0f / (1.0f + expf(-(a3 * norm + bb.w)));
        *(float4*)(out + (size_t)nid * OUT_F + q * 4) = o;
    }
}

// ---------------------------------------------------------------------------
extern "C" void kernel_launch(void* const* d_in, const int* in_sizes, int n_in,
                              void* d_out, int out_size, void* d_ws, size_t ws_size,
                              hipStream_t stream) {
    const float* feat = (const float*)d_in[0];
    const int* src    = (const int*)d_in[1];
    const int* dst    = (const int*)d_in[2];
    const float* W    = (const float*)d_in[3];
    const float* b    = (const float*)d_in[4];
    float* out = (float*)d_out;

    char* ws = (char*)d_ws;
    size_t off = 0;
    ushort* h = (ushort*)(ws + off);        off += (size_t)N_NODES * OUT_F * 2;  // 6.4 MB
    float* normS = (float*)(ws + off);      off += (size_t)N_NODES * 4;          // 200 KB
    uint* ptrdeg = (uint*)(ws + off);       off += (size_t)N_NODES * 4;          // 200 KB
    int* bcnt = (int*)(ws + off);           off += (size_t)2 * NB * 4;           // bcntD|bcntS
    ushort* Wpk = (ushort*)(ws + off);      off += (size_t)IN_F * OUT_F * 2;     // 32 KB
    uint* pairsD = (uint*)(ws + off);       off += (size_t)NB * CAP * 4;         // 4.8 MB
    ushort* srcloc = (ushort*)(ws + off);   off += (size_t)NB * CAP * 2;         // 2.4 MB
    ushort* sorted_src = (ushort*)(ws + off); off += (size_t)NB * CAP * 2;       // 2.4 MB
    int* bcntD = bcnt;
    int* bcntS = bcnt + NB;

    prep_kernel<<<9, 256, 0, stream>>>(bcnt, W, Wpk);

    fused_kernel<<<PARTA_BLOCKS + GEMM_BLOCKS, 512, 0, stream>>>(
        src, dst, bcntD, bcntS, pairsD, srcloc, feat, Wpk, h);

    bucket_kernel<<<NB, 1024, 0, stream>>>(srcloc, bcntS, normS,
                                           pairsD, bcntD, ptrdeg, sorted_src);

    gather_kernel<<<(N_NODES * 64 + 255) / 256, 256, 0, stream>>>(
        ptrdeg, sorted_src, normS, h, b, out);
}

// Round 22
// 68.033 us; speedup vs baseline: 1.1673x; 1.0017x over previous
//
#include <hip/hip_runtime.h>
#include <hip/hip_bf16.h>
#include <math.h>

#define N_NODES 50000
#define N_EDGES 800000
#define IN_F 256
#define OUT_F 64

#define BKT 256            // nodes per bucket
#define NB 196             // ceil(50000/256)
#define CAP 6144           // fixed per-bucket capacity (mean 4096, sigma 64)
#define PARTA_BLOCKS 400   // 800000/400 = 2000 edges/block
#define EPB (N_EDGES / PARTA_BLOCKS)   // 2000
#define GEMM_BM 32
#define GEMM_BLOCKS 782    // two BM=32 tiles per 512-thread block role
#define HIST_CHUNK 12500   // outdeg hist: 4 chunks x 16 slices = 64 blocks
#define HIST_BLOCKS 64

typedef __attribute__((ext_vector_type(8))) short bf16x8;
typedef __attribute__((ext_vector_type(4))) float f32x4;

__device__ __forceinline__ ushort f2bf(float x) {
    __hip_bfloat16 b = __float2bfloat16(x);   // RNE
    return *reinterpret_cast<ushort*>(&b);
}
__device__ __forceinline__ float bf_lo(uint v) { return __uint_as_float(v << 16); }
__device__ __forceinline__ float bf_hi(uint v) { return __uint_as_float(v & 0xffff0000u); }

// ---------------------------------------------------------------------------
// 0) prep: block 0 zeros bcntD; blocks 1..8 pack W into bf16 MFMA B-frag
//    layout; blocks 9+ zero outdeg (12500 int4).
// ---------------------------------------------------------------------------
__global__ __launch_bounds__(256) void prep_kernel(int* __restrict__ bcntD,
                                                   const float* __restrict__ W,
                                                   ushort* __restrict__ Wpk,
                                                   int4* __restrict__ outdeg4) {
    const int tid = threadIdx.x;
    if (blockIdx.x == 0) {
        for (int i = tid; i < NB; i += 256) bcntD[i] = 0;
    } else if (blockIdx.x < 9) {
        const int gid = (blockIdx.x - 1) * 256 + tid;   // 0..2047
        const int lane = gid & 63;
        const int ct = (gid >> 6) & 3;
        const int step = gid >> 8;
        const int kg = lane >> 4;
        const int n = lane & 15;
        const float* base = W + (size_t)(step * 32 + kg * 8) * OUT_F + ct * 16 + n;
        union { ushort u[8]; uint4 v; } pk;
        #pragma unroll
        for (int j = 0; j < 8; ++j) pk.u[j] = f2bf(base[(size_t)j * OUT_F]);
        ((uint4*)Wpk)[gid] = pk.v;
    } else {
        const int i = (blockIdx.x - 9) * 256 + tid;
        if (i < N_NODES / 4) outdeg4[i] = (int4){0, 0, 0, 0};
    }
}

// ---------------------------------------------------------------------------
// 1) fused: three roles overlapped in one launch —
//    partA (dst-only bucket-partition, LDS-atomic-bound),
//    hist  (outdeg LDS histogram, LDS/latency-bound),
//    gemm  (global_load_lds + MFMA, BW/MFMA-bound).
//    bi<800: odd=partA(bi>>1), even=gemm(bi>>1);
//    bi in [800,928): odd=hist((bi-800)>>1), even=gemm(400+((bi-800)>>1));
//    bi>=928: gemm(bi-464).
// ---------------------------------------------------------------------------
__global__ __launch_bounds__(512) void fused_kernel(const int* __restrict__ src,
                                                    const int* __restrict__ dst,
                                                    int* __restrict__ bcntD,
                                                    uint* __restrict__ pairsD,
                                                    int* __restrict__ outdeg,
                                                    const float* __restrict__ feat,
                                                    const ushort* __restrict__ Wpk,
                                                    ushort* __restrict__ h) {
    __shared__ __align__(16) char smem[65536];
    const int bi = blockIdx.x;
    const int tid = threadIdx.x;

    if (bi < 2 * PARTA_BLOCKS && (bi & 1)) {
        // ---------------- partA role (dst path only) ------------------------
        int2* ed    = (int2*)smem;                    // 16000
        uint* stgD  = (uint*)(smem + 16000);          //  8000 -> 24000
        int* lcntD  = (int*)(smem + 24000);           //  1024 -> 25024
        int* ldofD  = (int*)(smem + 25024);           //  1024 -> 26048
        int* lbaseD = (int*)(smem + 26048);           //   784 -> 26832
        int* wtotD  = (int*)(smem + 26832);           //    16
        const int id = bi >> 1;
        const int n4 = EPB / 4;   // 500

        for (int i = tid; i < 256; i += 512) lcntD[i] = 0;
        __syncthreads();

        const int4* t4 = (const int4*)(dst + (size_t)id * EPB);
        const int4* s4 = (const int4*)(src + (size_t)id * EPB);
        for (int i = tid; i < n4; i += 512) {
            const int4 d = t4[i];
            const int4 s = s4[i];
            ed[4 * i + 0] = (int2){d.x, s.x};
            ed[4 * i + 1] = (int2){d.y, s.y};
            ed[4 * i + 2] = (int2){d.z, s.z};
            ed[4 * i + 3] = (int2){d.w, s.w};
            atomicAdd(&lcntD[d.x >> 8], 1);
            atomicAdd(&lcntD[d.y >> 8], 1);
            atomicAdd(&lcntD[d.z >> 8], 1);
            atomicAdd(&lcntD[d.w >> 8], 1);
        }
        __syncthreads();

        for (int i = tid; i < NB; i += 512) {
            const int cD = lcntD[i];
            lbaseD[i] = cD ? atomicAdd(&bcntD[i], cD) : 0;
        }

        if (tid < 256) {
            const int lane = tid & 63;
            const int wave = tid >> 6;
            const int vD = lcntD[tid];
            int iD = vD;
            #pragma unroll
            for (int d = 1; d < 64; d <<= 1) {
                const int uD = __shfl_up(iD, d, 64);
                if (lane >= d) iD += uD;
            }
            if (lane == 63) wtotD[wave] = iD;
            ldofD[tid] = iD - vD;
        }
        __syncthreads();
        if (tid < 256) {
            const int wave = tid >> 6;
            int woD = 0;
            #pragma unroll
            for (int w = 0; w < 4; ++w)
                if (w < wave) woD += wtotD[w];
            ldofD[tid] += woD;
            lcntD[tid] = 0;      // reuse as cursor
        }
        __syncthreads();

        for (int i = tid; i < EPB; i += 512) {
            const int2 e = ed[i];
            const int bx = e.x >> 8;
            const int pos = atomicAdd(&lcntD[bx], 1);
            stgD[ldofD[bx] + pos] =
                ((uint)bx << 24) | ((uint)(e.x & 255) << 16) | (uint)e.y;
        }
        __syncthreads();

        for (int i = tid; i < EPB; i += 512) {
            const uint pv = stgD[i];
            const int bD = (int)(pv >> 24);
            pairsD[(size_t)bD * CAP + lbaseD[bD] + (i - ldofD[bD])] = pv & 0xFFFFFFu;
        }
    } else if (bi >= 2 * PARTA_BLOCKS && bi < 2 * PARTA_BLOCKS + 2 * HIST_BLOCKS
               && (bi & 1)) {
        // ---------------- hist role: outdeg LDS histogram -------------------
        int* cnt = (int*)smem;   // 50000 B
        const int id = (bi - 2 * PARTA_BLOCKS) >> 1;   // 0..63
        const int chunk = id >> 4;
        const int slice = id & 15;
        const int base = chunk * HIST_CHUNK;

        for (int i = tid; i < HIST_CHUNK; i += 512) cnt[i] = 0;
        __syncthreads();

        const int4* s4 = (const int4*)(src + (size_t)slice * (N_EDGES / 16));
        for (int i = tid; i < (N_EDGES / 16) / 4; i += 512) {
            const int4 v = s4[i];
            int r;
            r = v.x - base; if ((unsigned)r < (unsigned)HIST_CHUNK) atomicAdd(&cnt[r], 1);
            r = v.y - base; if ((unsigned)r < (unsigned)HIST_CHUNK) atomicAdd(&cnt[r], 1);
            r = v.z - base; if ((unsigned)r < (unsigned)HIST_CHUNK) atomicAdd(&cnt[r], 1);
            r = v.w - base; if ((unsigned)r < (unsigned)HIST_CHUNK) atomicAdd(&cnt[r], 1);
        }
        __syncthreads();

        for (int i = tid; i < HIST_CHUNK; i += 512) {
            const int c = cnt[i];
            if (c) atomicAdd(&outdeg[base + i], c);
        }
    } else {
        // ---------------- gemm role: two BM=32 tiles ------------------------
        const int id = (bi < 2 * PARTA_BLOCKS) ? (bi >> 1)
                     : (bi < 2 * PARTA_BLOCKS + 2 * HIST_BLOCKS)
                         ? (PARTA_BLOCKS + ((bi - 2 * PARTA_BLOCKS) >> 1))
                         : (bi - PARTA_BLOCKS - HIST_BLOCKS);
        const int half = tid >> 8;           // 0/1: which tile
        const int t = tid & 255;
        const int lane = t & 63;
        const int wave = t >> 6;             // 0..3 within half
        const int m = lane & 15;
        const int g = lane >> 4;
        const int rowBase = (id * 2 + half) * GEMM_BM;
        float* ftile = (float*)(smem + (size_t)half * 32768);
        const char* fb = (const char*)feat;

        #pragma unroll
        for (int it = 0; it < 8; ++it) {
            const int R = it * 4 + wave;                  // tile row 0..31
            const int off = (lane * 16) ^ ((R & 7) << 4); // swizzled src chunk
            int grow = rowBase + R;
            if (grow >= N_NODES) grow = N_NODES - 1;      // clamp (dup row)
            __builtin_amdgcn_global_load_lds(
                (const __attribute__((address_space(1))) void*)(fb + ((size_t)grow << 10) + off),
                (__attribute__((address_space(3))) void*)((char*)ftile + it * 4096 + wave * 1024),
                16, 0, 0);
        }
        __syncthreads();

        const int rowHalf = wave & 1;
        const int colHalf = wave >> 1;

        f32x4 acc[2];
        acc[0] = (f32x4){0.f, 0.f, 0.f, 0.f};
        acc[1] = (f32x4){0.f, 0.f, 0.f, 0.f};

        const int Rr = rowHalf * 16 + m;
        const int swz = (Rr & 7) << 4;
        const char* rowb = (const char*)ftile + (Rr << 10);
        const bf16x8* wp = (const bf16x8*)Wpk;

        #pragma unroll
        for (int step = 0; step < 8; ++step) {
            const int kb = step * 128 + g * 32;
            const float4 a0 = *(const float4*)(rowb + (kb ^ swz));
            const float4 a1 = *(const float4*)(rowb + ((kb + 16) ^ swz));
            bf16x8 aa;
            aa[0] = (short)f2bf(a0.x); aa[1] = (short)f2bf(a0.y);
            aa[2] = (short)f2bf(a0.z); aa[3] = (short)f2bf(a0.w);
            aa[4] = (short)f2bf(a1.x); aa[5] = (short)f2bf(a1.y);
            aa[6] = (short)f2bf(a1.z); aa[7] = (short)f2bf(a1.w);
            #pragma unroll
            for (int ct = 0; ct < 2; ++ct)
                acc[ct] = __builtin_amdgcn_mfma_f32_16x16x32_bf16(
                    aa, wp[(step * 4 + colHalf * 2 + ct) * 64 + lane], acc[ct], 0, 0, 0);
        }

        #pragma unroll
        for (int j = 0; j < 4; ++j) {
            const int row = rowBase + rowHalf * 16 + g * 4 + j;
            if (row < N_NODES) {
                #pragma unroll
                for (int ct = 0; ct < 2; ++ct)
                    h[(size_t)row * OUT_F + colHalf * 32 + ct * 16 + m] = f2bf(acc[ct][j]);
            }
        }
    }
}

// ---------------------------------------------------------------------------
// 2) bucket: dst sort only (phase-1 deleted — outdeg comes from hist role).
//    Writes normS (contiguous read of outdeg) + packed ptrdeg.
// ---------------------------------------------------------------------------
__global__ __launch_bounds__(1024) void bucket_kernel(const int* __restrict__ outdeg,
                                                      float* __restrict__ normS,
                                                      const uint* __restrict__ pairsD,
                                                      const int* __restrict__ bcntD,
                                                      uint* __restrict__ ptrdeg,
                                                      ushort* __restrict__ sorted_src) {
    __shared__ int cnt[BKT];
    __shared__ int loff[BKT];
    __shared__ int wtot[4];
    const int bb = blockIdx.x;
    const int tid = threadIdx.x;
    const int node = bb * BKT + tid;   // valid meaning only for tid<256

    if (tid < BKT) {
        cnt[tid] = 0;
        if (node < N_NODES)
            normS[node] = rsqrtf(fmaxf((float)outdeg[node], 1.0f));
    }
    __syncthreads();
    const int nD = bcntD[bb];
    const uint* pb = pairsD + (size_t)bb * CAP;
    for (int i = tid; i < nD; i += 1024) atomicAdd(&cnt[(pb[i] >> 16) & 255u], 1);
    __syncthreads();

    // scan on waves 0-3
    if (tid < BKT) {
        const int lane = tid & 63;
        const int wave = tid >> 6;
        const int v = cnt[tid];
        int incl = v;
        #pragma unroll
        for (int d = 1; d < 64; d <<= 1) {
            int u = __shfl_up(incl, d, 64);
            if (lane >= d) incl += u;
        }
        if (lane == 63) wtot[wave] = incl;
        loff[tid] = incl - v;            // temp: intra-wave exclusive
    }
    __syncthreads();
    if (tid < BKT) {
        const int wave = tid >> 6;
        int woff = 0;
        #pragma unroll
        for (int w = 0; w < 4; ++w)
            if (w < wave) woff += wtot[w];
        const int ex = woff + loff[tid];
        loff[tid] = ex;
        const int v = cnt[tid];
        cnt[tid] = 0;                    // reuse as per-local cursor
        if (node < N_NODES)
            ptrdeg[node] = (uint)(bb * CAP + ex) | ((uint)v << 21);
    }
    __syncthreads();

    for (int i = tid; i < nD; i += 1024) {
        const uint p = pb[i];
        const int local = (int)((p >> 16) & 255u);
        const int pos = atomicAdd(&cnt[local], 1);
        sorted_src[(size_t)bb * CAP + loff[local] + pos] = (ushort)(p & 0xFFFFu);
    }
}

// ---------------------------------------------------------------------------
// 3) Gather + epilogue: one wave per dst node, quarter-wave per edge,
//    gathered rows scaled by normS[src]; packed ptrdeg.
// ---------------------------------------------------------------------------
__global__ __launch_bounds__(256) void gather_kernel(const uint* __restrict__ ptrdeg,
                                                     const ushort* __restrict__ sorted_src,
                                                     const float* __restrict__ normS,
                                                     const ushort* __restrict__ h,
                                                     const float* __restrict__ b,
                                                     float* __restrict__ out) {
    const int lane = threadIdx.x & 63;
    const int q = lane & 15;           // col group: cols q*4 .. q*4+3
    const int g = lane >> 4;           // edge slot 0..3
    int nid = (int)((blockIdx.x * (size_t)blockDim.x + threadIdx.x) >> 6);
    if (nid >= N_NODES) return;
    nid = __builtin_amdgcn_readfirstlane(nid);

    const uint pd = ptrdeg[nid];
    const int beg = (int)(pd & 0x1FFFFFu);
    const int deg = (int)(pd >> 21);

    float a0 = 0.f, a1 = 0.f, a2 = 0.f, a3 = 0.f;
    const int nfull = deg >> 2;
    int e = beg + g;
    #pragma unroll 4
    for (int i = 0; i < nfull; ++i) {
        const int s = (int)sorted_src[e];
        e += 4;
        const float ns = normS[s];
        const uint2 v = *(const uint2*)(h + (size_t)s * OUT_F + q * 4);
        a0 = fmaf(ns, bf_lo(v.x), a0); a1 = fmaf(ns, bf_hi(v.x), a1);
        a2 = fmaf(ns, bf_lo(v.y), a2); a3 = fmaf(ns, bf_hi(v.y), a3);
    }
    const int rem = deg & 3;
    if (g < rem) {
        const int s = (int)sorted_src[beg + (deg & ~3) + g];
        const float ns = normS[s];
        const uint2 v = *(const uint2*)(h + (size_t)s * OUT_F + q * 4);
        a0 = fmaf(ns, bf_lo(v.x), a0); a1 = fmaf(ns, bf_hi(v.x), a1);
        a2 = fmaf(ns, bf_lo(v.y), a2); a3 = fmaf(ns, bf_hi(v.y), a3);
    }
    a0 += __shfl_xor(a0, 16, 64); a1 += __shfl_xor(a1, 16, 64);
    a2 += __shfl_xor(a2, 16, 64); a3 += __shfl_xor(a3, 16, 64);
    a0 += __shfl_xor(a0, 32, 64); a1 += __shfl_xor(a1, 32, 64);
    a2 += __shfl_xor(a2, 32, 64); a3 += __shfl_xor(a3, 32, 64);

    if (g == 0) {
        const float norm = rsqrtf(fmaxf((float)deg, 1.0f));
        const float4 bb = *(const float4*)(b + q * 4);
        float4 o;
        o.x = 1.0f / (1.0f + expf(-(a0 * norm + bb.x)));
        o.y = 1.0f / (1.0f + expf(-(a1 * norm + bb.y)));
        o.z = 1.0f / (1.0f + expf(-(a2 * norm + bb.z)));
        o.w = 1.0f / (1.0f + expf(-(a3 * norm + bb.w)));
        *(float4*)(out + (size_t)nid * OUT_F + q * 4) = o;
    }
}

// ---------------------------------------------------------------------------
extern "C" void kernel_launch(void* const* d_in, const int* in_sizes, int n_in,
                              void* d_out, int out_size, void* d_ws, size_t ws_size,
                              hipStream_t stream) {
    const float* feat = (const float*)d_in[0];
    const int* src    = (const int*)d_in[1];
    const int* dst    = (const int*)d_in[2];
    const float* W    = (const float*)d_in[3];
    const float* b    = (const float*)d_in[4];
    float* out = (float*)d_out;

    char* ws = (char*)d_ws;
    size_t off = 0;
    ushort* h = (ushort*)(ws + off);        off += (size_t)N_NODES * OUT_F * 2;  // 6.4 MB
    float* normS = (float*)(ws + off);      off += (size_t)N_NODES * 4;          // 200 KB
    uint* ptrdeg = (uint*)(ws + off);       off += (size_t)N_NODES * 4;          // 200 KB
    int* outdeg = (int*)(ws + off);         off += (size_t)N_NODES * 4;          // 200 KB
    int* bcntD = (int*)(ws + off);          off += (size_t)NB * 4 + 16;
    ushort* Wpk = (ushort*)(ws + off);      off += (size_t)IN_F * OUT_F * 2;     // 32 KB
    uint* pairsD = (uint*)(ws + off);       off += (size_t)NB * CAP * 4;         // 4.8 MB
    ushort* sorted_src = (ushort*)(ws + off); off += (size_t)NB * CAP * 2;       // 2.4 MB

    prep_kernel<<<9 + (N_NODES / 4 + 255) / 256, 256, 0, stream>>>(
        bcntD, W, Wpk, (int4*)outdeg);

    fused_kernel<<<PARTA_BLOCKS + HIST_BLOCKS + GEMM_BLOCKS, 512, 0, stream>>>(
        src, dst, bcntD, pairsD, outdeg, feat, Wpk, h);

    bucket_kernel<<<NB, 1024, 0, stream>>>(outdeg, normS,
                                           pairsD, bcntD, ptrdeg, sorted_src);

    gather_kernel<<<(N_NODES * 64 + 255) / 256, 256, 0, stream>>>(
        ptrdeg, sorted_src, normS, h, b, out);
}